// Round 1
// baseline (515.547 us; speedup 1.0000x reference)
//
#include <hip/hip_runtime.h>
#include <hip/hip_bf16.h>

// PGNN layer for MI355X (gfx950).
// Reference:
//   u = feature @ W_u + b_u            [N,64]
//   v = feature @ W_v + b_v            [N,64]
//   msg[e] = v[dst[e]] + u[src[e]] * sp_dist[e]
//   msgs = relu(msg[anchor_eid]).reshape(N, K, 64)
//   out_position  = msgs @ W_out + b_out   -> [N,K]
//   out_structure = mean_k(msgs)           -> [N,64]
//
// N=50000, K=64, E=N*K=3.2M, IN_DIM=256, OUT_DIM=64.
// d_out = out_position (N*K floats) ++ out_structure (N*64 floats)

#define IN_DIM 256
#define OUT_DIM 64
#define KANCH 64

// ---------------- Kernel 1: fused projection GEMM ----------------
// Computes uv[N][128]: cols 0..63 = u_feat, cols 64..127 = v_feat.
// Tiled fp32 GEMM: BM=64 nodes, BN=128 (both outputs), BK=32.
// 256 threads as 16x16; each thread computes TM=4 x TN=8 accumulators.
__global__ __launch_bounds__(256) void pgnn_proj_kernel(
    const float* __restrict__ feature,
    const float* __restrict__ Wu, const float* __restrict__ bu,
    const float* __restrict__ Wv, const float* __restrict__ bv,
    float* __restrict__ uv, int N)
{
    constexpr int BM = 64, BN = 128, BK = 32;
    __shared__ float sA[BK][BM + 1];   // A stored transposed: sA[k][m]
    __shared__ float sB[BK][BN + 4];

    const int tid  = threadIdx.x;
    const int row0 = blockIdx.x * BM;
    const int tr   = tid >> 4;   // 0..15 -> node sub-row * 4
    const int tc   = tid & 15;   // 0..15 -> col * 8

    float acc[4][8];
    #pragma unroll
    for (int i = 0; i < 4; ++i)
        #pragma unroll
        for (int j = 0; j < 8; ++j) acc[i][j] = 0.f;

    for (int k0 = 0; k0 < IN_DIM; k0 += BK) {
        // Stage A tile (64 nodes x 32 k), transposed into sA[k][m].
        #pragma unroll
        for (int i = 0; i < 8; ++i) {
            int flat = tid + i * 256;      // 0..2047
            int r = flat >> 5;             // node within tile 0..63
            int c = flat & 31;             // k within tile
            int gr = row0 + r;
            float va = (gr < N) ? feature[(size_t)gr * IN_DIM + k0 + c] : 0.f;
            sA[c][r] = va;
        }
        // Stage B tile (32 k x 128 cols): cols 0..63 from Wu, 64..127 from Wv.
        #pragma unroll
        for (int i = 0; i < 16; ++i) {
            int flat = tid + i * 256;      // 0..4095
            int r = flat >> 7;             // k within tile 0..31
            int c = flat & 127;            // col 0..127
            float vb = (c < OUT_DIM) ? Wu[(k0 + r) * OUT_DIM + c]
                                     : Wv[(k0 + r) * OUT_DIM + (c - OUT_DIM)];
            sB[r][c] = vb;
        }
        __syncthreads();

        #pragma unroll
        for (int k = 0; k < BK; ++k) {
            float a[4], b[8];
            #pragma unroll
            for (int i = 0; i < 4; ++i) a[i] = sA[k][tr * 4 + i];
            #pragma unroll
            for (int j = 0; j < 8; ++j) b[j] = sB[k][tc * 8 + j];
            #pragma unroll
            for (int i = 0; i < 4; ++i)
                #pragma unroll
                for (int j = 0; j < 8; ++j)
                    acc[i][j] = fmaf(a[i], b[j], acc[i][j]);
        }
        __syncthreads();
    }

    // Epilogue: add bias, write uv.
    #pragma unroll
    for (int i = 0; i < 4; ++i) {
        int gr = row0 + tr * 4 + i;
        if (gr >= N) continue;
        #pragma unroll
        for (int j = 0; j < 8; ++j) {
            int c = tc * 8 + j;
            float bias = (c < OUT_DIM) ? bu[c] : bv[c - OUT_DIM];
            uv[(size_t)gr * 128 + c] = acc[i][j] + bias;
        }
    }
}

// ---------------- Kernel 2: anchor gather / message / outputs ----------------
// One 64-lane wave per node; lane = output dim d. 4 waves (4 nodes) per block.
// Per anchor k: broadcast (src,dst,sp) from lane k, gather 256B rows of u/v,
// relu, accumulate mean, butterfly-reduce the W_out dot.
__global__ __launch_bounds__(256) void pgnn_edge_kernel(
    const float* __restrict__ uv,
    const int*   __restrict__ src,
    const int*   __restrict__ dst,
    const float* __restrict__ sp_dist,
    const int*   __restrict__ anchor_eid,
    const float* __restrict__ W_out,
    const float* __restrict__ b_out,
    float* __restrict__ out_pos,     // [N,K]
    float* __restrict__ out_struct,  // [N,64]
    int N)
{
    const int lane = threadIdx.x & 63;
    const int wave = threadIdx.x >> 6;
    const int n = blockIdx.x * 4 + wave;
    if (n >= N) return;

    // Per-lane anchor metadata: lane k holds anchor k's (src,dst,sp).
    const int e  = anchor_eid[(size_t)n * KANCH + lane];
    const int  s_my  = src[e];
    const int  d_my  = dst[e];
    const float sp_my = sp_dist[e];

    const float w  = W_out[lane];
    const float bo = b_out[0];

    float acc = 0.f;   // sum over k of msgs[n][k][lane]
    float pos = 0.f;   // out_position[n][lane] (picked up when k == lane)

    #pragma unroll 8
    for (int k = 0; k < KANCH; ++k) {
        const int   ss = __shfl(s_my, k);
        const int   dd = __shfl(d_my, k);
        const float sp = __shfl(sp_my, k);

        const float u = uv[(size_t)ss * 128 + lane];        // u_feat[ss][lane]
        const float v = uv[(size_t)dd * 128 + 64 + lane];   // v_feat[dd][lane]
        float m = fmaf(u, sp, v);
        m = fmaxf(m, 0.f);

        acc += m;

        // dot(m, W_out) across the wave
        float p = m * w;
        #pragma unroll
        for (int off = 32; off > 0; off >>= 1)
            p += __shfl_xor(p, off);
        if (lane == k) pos = p + bo;
    }

    out_pos[(size_t)n * KANCH + lane]   = pos;
    out_struct[(size_t)n * OUT_DIM + lane] = acc * (1.f / (float)KANCH);
}

extern "C" void kernel_launch(void* const* d_in, const int* in_sizes, int n_in,
                              void* d_out, int out_size, void* d_ws, size_t ws_size,
                              hipStream_t stream) {
    const float* feature    = (const float*)d_in[0];
    const int*   src        = (const int*)  d_in[1];
    const int*   dst        = (const int*)  d_in[2];
    const float* sp_dist    = (const float*)d_in[3];
    const int*   anchor_eid = (const int*)  d_in[4];
    // d_in[5] = dists_max: shape-only in the reference, numerically unused.
    const float* W_u   = (const float*)d_in[6];
    const float* b_u   = (const float*)d_in[7];
    const float* W_v   = (const float*)d_in[8];
    const float* b_v   = (const float*)d_in[9];
    const float* W_out = (const float*)d_in[10];
    const float* b_out = (const float*)d_in[11];

    const int N = in_sizes[0] / IN_DIM;           // 50000
    float* uv = (float*)d_ws;                     // [N][128], 25.6 MB

    float* out_pos    = (float*)d_out;            // [N,K]
    float* out_struct = (float*)d_out + (size_t)N * KANCH;

    {
        constexpr int BM = 64;
        dim3 grid((N + BM - 1) / BM);
        pgnn_proj_kernel<<<grid, 256, 0, stream>>>(feature, W_u, b_u, W_v, b_v, uv, N);
    }
    {
        dim3 grid((N + 3) / 4);
        pgnn_edge_kernel<<<grid, 256, 0, stream>>>(uv, src, dst, sp_dist, anchor_eid,
                                                   W_out, b_out, out_pos, out_struct, N);
    }
}

// Round 3
// 324.094 us; speedup vs baseline: 1.5907x; 1.5907x over previous
//
#include <hip/hip_runtime.h>
#include <hip/hip_fp16.h>
#include <hip/hip_bf16.h>

// PGNN layer for MI355X (gfx950).
//   u = feature @ W_u + b_u            [N,64]
//   v = feature @ W_v + b_v            [N,64]
//   msg[e] = v[dst[e]] + u[src[e]] * sp_dist[e]
//   msgs = relu(msg[anchor_eid]).reshape(N, K, 64)
//   out_position  = msgs @ W_out + b_out   -> [N,K]
//   out_structure = mean_k(msgs)           -> [N,64]
// N=50000, K=64, E=N*K=3.2M, IN_DIM=256, OUT_DIM=64.
// d_out = out_position (N*K floats) ++ out_structure (N*64 floats)
//
// R2 changes vs R1 (resubmitted in R3 after infra failure):
//  - uv stored fp16 (halves the 1.33 GB gather fetch; err ~1.6e-4 << tolerance)
//  - edge reduce: LDS-transpose per 16-k chunk instead of 6-shfl butterfly/k
//    (DS ops/node 576 -> ~136, no 6-deep dependent chains)
//  - (src,dst,sp) broadcast via readlane (constant lane after full unroll)
//  - proj: TM=TN=8 tile, BK=16, 128-thread blocks (denser FMA/LDS-read ratio)

#define IN_DIM 256
#define OUT_DIM 64
#define KANCH 64

// ---------------- Kernel 1: fused projection GEMM (fp32 -> fp16 uv) --------
// uv[N][128]: cols 0..63 = u_feat, cols 64..127 = v_feat (as __half).
// BM=64 nodes, BN=128 cols, BK=16. 128 threads; each computes 8x8.
__global__ __launch_bounds__(128) void pgnn_proj_kernel(
    const float* __restrict__ feature,
    const float* __restrict__ Wu, const float* __restrict__ bu,
    const float* __restrict__ Wv, const float* __restrict__ bv,
    __half* __restrict__ uv, int N)
{
    constexpr int BM = 64, BK = 16, PA = 68, PB = 132;
    __shared__ float sA[BK * PA];   // sA[k][m], transposed A tile
    __shared__ float sB[BK * PB];   // sB[k][c]

    const int tid  = threadIdx.x;
    const int row0 = blockIdx.x * BM;
    const int tr   = tid >> 4;   // 0..7 -> rows tr*8..tr*8+7
    const int tc   = tid & 15;   // 0..15 -> cols tc*8..tc*8+7

    float acc[8][8];
    #pragma unroll
    for (int i = 0; i < 8; ++i)
        #pragma unroll
        for (int j = 0; j < 8; ++j) acc[i][j] = 0.f;

    for (int k0 = 0; k0 < IN_DIM; k0 += BK) {
        // Stage A tile (64 m x 16 k) transposed: 256 float4, 2 per thread.
        #pragma unroll
        for (int i = 0; i < 2; ++i) {
            int f  = tid + i * 128;        // 0..255
            int m  = f >> 2, c4 = f & 3;
            int gr = row0 + m;
            float4 va = make_float4(0.f, 0.f, 0.f, 0.f);
            if (gr < N)
                va = *reinterpret_cast<const float4*>(
                        &feature[(size_t)gr * IN_DIM + k0 + c4 * 4]);
            sA[(c4 * 4 + 0) * PA + m] = va.x;
            sA[(c4 * 4 + 1) * PA + m] = va.y;
            sA[(c4 * 4 + 2) * PA + m] = va.z;
            sA[(c4 * 4 + 3) * PA + m] = va.w;
        }
        // Stage B tile (16 k x 128 c): 512 float4, 4 per thread.
        #pragma unroll
        for (int i = 0; i < 4; ++i) {
            int f  = tid + i * 128;        // 0..511
            int kk = f >> 5, c4 = f & 31;
            float4 vb;
            if (c4 < 16)
                vb = *reinterpret_cast<const float4*>(&Wu[(k0 + kk) * OUT_DIM + c4 * 4]);
            else
                vb = *reinterpret_cast<const float4*>(&Wv[(k0 + kk) * OUT_DIM + (c4 - 16) * 4]);
            *reinterpret_cast<float4*>(&sB[kk * PB + c4 * 4]) = vb;
        }
        __syncthreads();

        #pragma unroll
        for (int k = 0; k < BK; ++k) {
            float4 a0 = *reinterpret_cast<const float4*>(&sA[k * PA + tr * 8]);
            float4 a1 = *reinterpret_cast<const float4*>(&sA[k * PA + tr * 8 + 4]);
            float4 b0 = *reinterpret_cast<const float4*>(&sB[k * PB + tc * 8]);
            float4 b1 = *reinterpret_cast<const float4*>(&sB[k * PB + tc * 8 + 4]);
            float a[8] = {a0.x, a0.y, a0.z, a0.w, a1.x, a1.y, a1.z, a1.w};
            float b[8] = {b0.x, b0.y, b0.z, b0.w, b1.x, b1.y, b1.z, b1.w};
            #pragma unroll
            for (int i = 0; i < 8; ++i)
                #pragma unroll
                for (int j = 0; j < 8; ++j)
                    acc[i][j] = fmaf(a[i], b[j], acc[i][j]);
        }
        __syncthreads();
    }

    // Epilogue: bias, convert to fp16, write as __half2 pairs.
    #pragma unroll
    for (int i = 0; i < 8; ++i) {
        int gr = row0 + tr * 8 + i;
        if (gr >= N) continue;
        #pragma unroll
        for (int j = 0; j < 8; j += 2) {
            int c0 = tc * 8 + j;
            float bias0 = (c0 < OUT_DIM) ? bu[c0] : bv[c0 - OUT_DIM];
            float bias1 = (c0 + 1 < OUT_DIM) ? bu[c0 + 1] : bv[c0 + 1 - OUT_DIM];
            __half2 h = __floats2half2_rn(acc[i][j] + bias0, acc[i][j + 1] + bias1);
            *reinterpret_cast<__half2*>(&uv[(size_t)gr * 128 + c0]) = h;
        }
    }
}

// ---------------- Kernel 2: anchor gather / message / outputs ---------------
// One 64-lane wave per node, lane = dim d. 4 waves/block.
// K processed in 4 chunks of 16. Pass1: gather+message+struct-acc+LDS store of
// p = relu(m)*w[d]. Pass2: row-sum the [16][64] tile (16 reads + 2 shfl/lane).
#define TPAD 67
__global__ __launch_bounds__(256) void pgnn_edge_kernel(
    const __half* __restrict__ uv,
    const int*    __restrict__ src,
    const int*    __restrict__ dst,
    const float*  __restrict__ sp_dist,
    const int*    __restrict__ anchor_eid,
    const float*  __restrict__ W_out,
    const float*  __restrict__ b_out,
    float* __restrict__ out_pos,     // [N,64]
    float* __restrict__ out_struct,  // [N,64]
    int N)
{
    const int lane = threadIdx.x & 63;
    const int wv   = threadIdx.x >> 6;
    const int n    = blockIdx.x * 4 + wv;
    if (n >= N) return;   // wave-uniform; no block-wide syncs below

    __shared__ float tile[4][16 * TPAD];
    float* t = tile[wv];

    const int   e     = anchor_eid[(size_t)n * KANCH + lane];
    const int   s_my  = src[e];
    const int   d_my  = dst[e];
    const float sp_my = sp_dist[e];

    const float w  = W_out[lane];
    const float bo = b_out[0];

    float acc = 0.f;

    #pragma unroll
    for (int c = 0; c < 4; ++c) {
        #pragma unroll
        for (int kk = 0; kk < 16; ++kk) {
            const int k = c * 16 + kk;   // compile-time constant after unroll
            const int   ss = __builtin_amdgcn_readlane(s_my, k);
            const int   dd = __builtin_amdgcn_readlane(d_my, k);
            const float sp = __int_as_float(
                __builtin_amdgcn_readlane(__float_as_int(sp_my), k));

            const float u = __half2float(uv[(size_t)ss * 128 + lane]);
            const float v = __half2float(uv[(size_t)dd * 128 + 64 + lane]);
            float m = fmaxf(fmaf(u, sp, v), 0.f);

            acc += m;
            t[kk * TPAD + lane] = m * w;
        }
        asm volatile("s_waitcnt lgkmcnt(0)" ::: "memory");

        // Pass2: pos[k = c*16 + r] = sum_d t[r][d]; lane (r,q) sums 16 d's.
        const int r = lane & 15, q = lane >> 4;
        float s = 0.f;
        #pragma unroll
        for (int j = 0; j < 16; ++j) s += t[r * TPAD + q * 16 + j];
        s += __shfl_xor(s, 16);
        s += __shfl_xor(s, 32);
        if (q == c) out_pos[(size_t)n * KANCH + lane] = s + bo;  // k == lane here
        asm volatile("s_waitcnt lgkmcnt(0)" ::: "memory");
    }

    out_struct[(size_t)n * OUT_DIM + lane] = acc * (1.f / (float)KANCH);
}

extern "C" void kernel_launch(void* const* d_in, const int* in_sizes, int n_in,
                              void* d_out, int out_size, void* d_ws, size_t ws_size,
                              hipStream_t stream) {
    const float* feature    = (const float*)d_in[0];
    const int*   src        = (const int*)  d_in[1];
    const int*   dst        = (const int*)  d_in[2];
    const float* sp_dist    = (const float*)d_in[3];
    const int*   anchor_eid = (const int*)  d_in[4];
    // d_in[5] = dists_max: shape-only in the reference, numerically unused.
    const float* W_u   = (const float*)d_in[6];
    const float* b_u   = (const float*)d_in[7];
    const float* W_v   = (const float*)d_in[8];
    const float* b_v   = (const float*)d_in[9];
    const float* W_out = (const float*)d_in[10];
    const float* b_out = (const float*)d_in[11];

    const int N = in_sizes[0] / IN_DIM;           // 50000
    __half* uv = (__half*)d_ws;                   // [N][128] fp16, 12.8 MB

    float* out_pos    = (float*)d_out;            // [N,K]
    float* out_struct = (float*)d_out + (size_t)N * KANCH;

    {
        constexpr int BM = 64;
        dim3 grid((N + BM - 1) / BM);
        pgnn_proj_kernel<<<grid, 128, 0, stream>>>(feature, W_u, b_u, W_v, b_v, uv, N);
    }
    {
        dim3 grid((N + 3) / 4);
        pgnn_edge_kernel<<<grid, 256, 0, stream>>>(uv, src, dst, sp_dist, anchor_eid,
                                                   W_out, b_out, out_pos, out_struct, N);
    }
}